// Round 4
// baseline (88.505 us; speedup 1.0000x reference)
//
#include <hip/hip_runtime.h>
#include <hip/hip_fp16.h>

// ---- problem constants ----
#define B_    4096
#define F_    39
#define D_    16
#define NKK0  50           // layer0 K=32 chunks (40h * 5a * 8j / 32)
#define NKK1  80           // layer1 K=32 chunks (64h * 5a * 8j / 32)
#define NKK   130
#define NRND  65           // rounds of 2 kk
#define WP_HALFS (NKK * 4096)   // 532480 halfs = 1.04 MB

typedef _Float16 f16x8  __attribute__((ext_vector_type(8)));
typedef float    f32x4  __attribute__((ext_vector_type(4)));
typedef float    f32x16 __attribute__((ext_vector_type(16)));

union FragAB { f16x8 h8; __half2 h2[4]; f32x4 f4; __half h[8]; };

__device__ __forceinline__ void gload_lds16(const void* g, void* l) {
    __builtin_amdgcn_global_load_lds(
        (const __attribute__((address_space(1))) void*)g,
        (__attribute__((address_space(3))) void*)l, 16, 0, 0);
}

// ---------- W pre-pack into 32x32x16 A-fragment order, a-major K ----------
// Wp[kkg][Mt][ks][lane][j]; o = Mt*32 + (lane&31); k-local = 8*(lane>>5)+j
__global__ __launch_bounds__(256) void prep_w(
    const float* __restrict__ W0, const float* __restrict__ W1,
    __half* __restrict__ Wp)
{
    int idx = blockIdx.x * 256 + threadIdx.x;
    if (idx >= WP_HALFS) return;
    int j   = idx & 7;
    int l   = (idx >> 3) & 63;
    int ks  = (idx >> 9) & 1;
    int Mt  = (idx >> 10) & 3;
    int kkg = idx >> 12;
    int o   = Mt * 32 + (l & 31);
    int sub = l >> 5;
    float v = 0.f;
    if (kkg < NKK0) {
        int u = 4 * kkg + 2 * ks + sub;            // < 200
        int a = u / 40, h = u - 40 * a, m = a * 8 + j;
        if (h < F_ && m < F_) v = W0[o * (F_ * F_) + h * F_ + m];
    } else {
        int u = 4 * (kkg - NKK0) + 2 * ks + sub;   // < 320
        int a = u >> 6, h = u & 63, m = a * 8 + j;
        if (m < F_) v = W1[o * (64 * F_) + h * F_ + m];
    }
    Wp[idx] = __float2half(v);
}

// ---------- one round = 2 kk (K=64); counted-vmcnt 3-deep pipeline ----------
template<int LL, int AA>
__device__ __forceinline__ void do_round(
    int rr, int t, int sub,
    const __half* xrowA, const __half* xrowB,
    const __half* nrowA, const __half* nrowB,
    const FragAB (&xmc)[2][5], f32x16 (&acc)[2][2],
    __half* WlFlat, int wl_thread,
    int& rd, int& rg, const __half* __restrict__ Wp)
{
    // wait: my round-rg loads done (round rg+1's 4 stay in flight), then barrier
    asm volatile("s_waitcnt vmcnt(4)" ::: "memory");
    __builtin_amdgcn_s_barrier();
    asm volatile("" ::: "memory");

    // issue stage for round rg+2 (dummy re-stage into dead buffer at tail,
    // keeps vmcnt counting uniform)
    {
        int sb = rd + 2; if (sb >= 3) sb -= 3;
        int rs = rg + 2; if (rs > NRND - 1) rs = NRND - 1;
        __half* dst = WlFlat + sb * 8192;
        const __half* src = Wp + (size_t)rs * 8192;
#pragma unroll
        for (int it = 0; it < 4; ++it)
            gload_lds16(src + it * 2048 + t * 8, dst + it * 2048 + t * 8);
    }

    const __half* wl  = WlFlat + rd * 8192 + wl_thread;
    const __half* hbA = LL ? nrowA : xrowA;
    const __half* hbB = LL ? nrowB : xrowB;

#pragma unroll
    for (int kk2 = 0; kk2 < 2; ++kk2) {
#pragma unroll
        for (int ks = 0; ks < 2; ++ks) {
            const int hoff = 8 * rr + 4 * kk2 + 2 * ks + sub;
            __half2 xa2 = __half2half2(hbA[hoff]);
            __half2 xb2 = __half2half2(hbB[hoff]);
            FragAB bA, bB;
#pragma unroll
            for (int q = 0; q < 4; ++q) {
                bA.h2[q] = __hmul2(xmc[0][AA].h2[q], xa2);
                bB.h2[q] = __hmul2(xmc[1][AA].h2[q], xb2);
            }
#pragma unroll
            for (int mt = 0; mt < 2; ++mt) {
                FragAB A;
                A.f4 = *(const f32x4*)(wl + kk2 * 4096 + mt * 1024 + ks * 512);
                acc[mt][0] = __builtin_amdgcn_mfma_f32_32x32x16_f16(
                    A.h8, bA.h8, acc[mt][0], 0, 0, 0);
                acc[mt][1] = __builtin_amdgcn_mfma_f32_32x32x16_f16(
                    A.h8, bB.h8, acc[mt][1], 0, 0, 0);
            }
        }
    }
    rd = (rd + 1 == 3) ? 0 : (rd + 1);
    ++rg;
}

// ---------- main: 512 blocks x 256 thr (4 waves); wave = 64 rows x 4 batches ----------
__global__ __launch_bounds__(256, 2) void cin_main(
    const float* __restrict__ x, const float* __restrict__ b0,
    const float* __restrict__ b1, const __half* __restrict__ Wp,
    float* __restrict__ out)
{
    __shared__ __align__(16) __half Wl[3][8192];      // 48 KB, 3-deep
    __shared__ __align__(16) __half xT[8][16][40];    // 10 KB  [bt][d][f]
    __shared__ __align__(16) __half nhT[8][16][68];   // 17 KB  [bt][d][h]
    __shared__ float bs0[128], bs1[128];              // 1 KB bias

    const int t    = threadIdx.x;
    const int w    = t >> 6, lane = t & 63;
    const int sub  = lane >> 5, bp = (lane >> 4) & 1, d = lane & 15;
    const int g    = w >> 1, hi = w & 1;
    const int gb   = blockIdx.x * 8;

    // bias -> LDS (so the main loop never touches global through compiler loads)
    if (t < 128) { bs0[t] = b0[t]; bs1[t] = b1[t]; }

    // xT fill: x[b][f][d] f32 -> xT[bt][d][f] fp16 (f=39 zero pad)
    for (int i = t; i < 8 * 156; i += 256) {
        int bt = i / 156, r2 = i - bt * 156;
        int f = r2 >> 2, dq = r2 & 3;
        const float4 v = *(const float4*)&x[((size_t)(gb + bt) * F_ + f) * D_ + dq * 4];
        xT[bt][dq * 4 + 0][f] = __float2half(v.x);
        xT[bt][dq * 4 + 1][f] = __float2half(v.y);
        xT[bt][dq * 4 + 2][f] = __float2half(v.z);
        xT[bt][dq * 4 + 3][f] = __float2half(v.w);
    }
    if (t < 128) xT[t >> 4][t & 15][39] = __float2half(0.f);

    // issue stage(0) -> buf0, stage(1) -> buf1 (8 loads in flight at loop top)
    __half* WlFlat = &Wl[0][0];
#pragma unroll
    for (int r0 = 0; r0 < 2; ++r0)
#pragma unroll
        for (int it = 0; it < 4; ++it)
            gload_lds16(Wp + (size_t)r0 * 8192 + it * 2048 + t * 8,
                        WlFlat + r0 * 8192 + it * 2048 + t * 8);

    asm volatile("s_waitcnt lgkmcnt(0)" ::: "memory");
    __builtin_amdgcn_s_barrier();
    asm volatile("" ::: "memory");

    // per-lane x row pointers + xm register cache (a = 0..4, compile-time idx)
    const int btA = g * 4 + bp;
    const int btB = g * 4 + 2 + bp;
    const __half* xrowA = &xT[btA][d][0];
    const __half* xrowB = &xT[btB][d][0];
    const __half* nrowA = &nhT[btA][d][0];
    const __half* nrowB = &nhT[btB][d][0];
    FragAB xmc[2][5];
#pragma unroll
    for (int a = 0; a < 5; ++a) {
        xmc[0][a].f4 = *(const f32x4*)(xrowA + a * 8);
        xmc[1][a].f4 = *(const f32x4*)(xrowB + a * 8);
    }

    // acc init = b0 (C/D row = (r&3)+8*(r>>2)+4*sub, col = lane&31)
    f32x16 acc[2][2];   // [mt][pair]
#pragma unroll
    for (int mt = 0; mt < 2; ++mt) {
        const int Mt = hi * 2 + mt;
#pragma unroll
        for (int r = 0; r < 16; ++r) {
            float bv = bs0[Mt * 32 + (r & 3) + 8 * (r >> 2) + 4 * sub];
            acc[mt][0][r] = bv; acc[mt][1][r] = bv;
        }
    }

    const int wl_thread = (hi * 2) * 1024 + lane * 8;
    int rd = 0, rg = 0;

    // ---- layer 0: 5 a-segments x 5 rounds (rounds 0..24) ----
#pragma unroll 1
    for (int rr = 0; rr < 5; ++rr) do_round<0,0>(rr,t,sub,xrowA,xrowB,nrowA,nrowB,xmc,acc,WlFlat,wl_thread,rd,rg,Wp);
#pragma unroll 1
    for (int rr = 0; rr < 5; ++rr) do_round<0,1>(rr,t,sub,xrowA,xrowB,nrowA,nrowB,xmc,acc,WlFlat,wl_thread,rd,rg,Wp);
#pragma unroll 1
    for (int rr = 0; rr < 5; ++rr) do_round<0,2>(rr,t,sub,xrowA,xrowB,nrowA,nrowB,xmc,acc,WlFlat,wl_thread,rd,rg,Wp);
#pragma unroll 1
    for (int rr = 0; rr < 5; ++rr) do_round<0,3>(rr,t,sub,xrowA,xrowB,nrowA,nrowB,xmc,acc,WlFlat,wl_thread,rd,rg,Wp);
#pragma unroll 1
    for (int rr = 0; rr < 5; ++rr) do_round<0,4>(rr,t,sub,xrowA,xrowB,nrowA,nrowB,xmc,acc,WlFlat,wl_thread,rd,rg,Wp);

    // ---- layer0 -> layer1 transition (no vmcnt drain; prefetches stay live) ----
    if (hi) {
        // rows 64..127 -> direct0 (out cols 0..63)
#pragma unroll
        for (int mt = 0; mt < 2; ++mt) {
            const int Mt = 2 + mt;
#pragma unroll
            for (int p = 0; p < 2; ++p) {
#pragma unroll
                for (int r = 0; r < 16; ++r) {
                    float v = fmaxf(acc[mt][p][r], 0.f);
                    v += __shfl_xor(v, 1); v += __shfl_xor(v, 2);
                    v += __shfl_xor(v, 4); v += __shfl_xor(v, 8);
                    if (d == 0) {
                        int row = Mt * 32 + (r & 3) + 8 * (r >> 2) + 4 * sub;
                        int b   = gb + g * 4 + p * 2 + bp;
                        out[(size_t)b * 192 + (row - 64)] = v;
                    }
                }
            }
        }
    } else {
        // rows 0..63 -> nhT (fp16), packed 4-half writes
#pragma unroll
        for (int mt = 0; mt < 2; ++mt) {
#pragma unroll
            for (int p = 0; p < 2; ++p) {
                __half* nr = (__half*)(p ? nrowB : nrowA);
#pragma unroll
                for (int rg4 = 0; rg4 < 4; ++rg4) {
                    union { __half h[4]; float2 f2; } pk;
#pragma unroll
                    for (int q = 0; q < 4; ++q)
                        pk.h[q] = __float2half(fmaxf(acc[mt][p][rg4 * 4 + q], 0.f));
                    int row0 = mt * 32 + 8 * rg4 + 4 * sub;
                    *(float2*)(nr + row0) = pk.f2;
                }
            }
        }
    }
    // re-init acc = b1 (from LDS)
#pragma unroll
    for (int mt = 0; mt < 2; ++mt) {
        const int Mt = hi * 2 + mt;
#pragma unroll
        for (int r = 0; r < 16; ++r) {
            float bv = bs1[Mt * 32 + (r & 3) + 8 * (r >> 2) + 4 * sub];
            acc[mt][0][r] = bv; acc[mt][1][r] = bv;
        }
    }
    asm volatile("s_waitcnt lgkmcnt(0)" ::: "memory");
    __builtin_amdgcn_s_barrier();
    asm volatile("" ::: "memory");

    // ---- layer 1: 5 a-segments x 8 rounds (rounds 25..64) ----
#pragma unroll 1
    for (int rr = 0; rr < 8; ++rr) do_round<1,0>(rr,t,sub,xrowA,xrowB,nrowA,nrowB,xmc,acc,WlFlat,wl_thread,rd,rg,Wp);
#pragma unroll 1
    for (int rr = 0; rr < 8; ++rr) do_round<1,1>(rr,t,sub,xrowA,xrowB,nrowA,nrowB,xmc,acc,WlFlat,wl_thread,rd,rg,Wp);
#pragma unroll 1
    for (int rr = 0; rr < 8; ++rr) do_round<1,2>(rr,t,sub,xrowA,xrowB,nrowA,nrowB,xmc,acc,WlFlat,wl_thread,rd,rg,Wp);
#pragma unroll 1
    for (int rr = 0; rr < 8; ++rr) do_round<1,3>(rr,t,sub,xrowA,xrowB,nrowA,nrowB,xmc,acc,WlFlat,wl_thread,rd,rg,Wp);
#pragma unroll 1
    for (int rr = 0; rr < 8; ++rr) do_round<1,4>(rr,t,sub,xrowA,xrowB,nrowA,nrowB,xmc,acc,WlFlat,wl_thread,rd,rg,Wp);

    // ---- final epilogue: direct1 -> out cols 64..191 ----
#pragma unroll
    for (int mt = 0; mt < 2; ++mt) {
        const int Mt = hi * 2 + mt;
#pragma unroll
        for (int p = 0; p < 2; ++p) {
#pragma unroll
            for (int r = 0; r < 16; ++r) {
                float v = fmaxf(acc[mt][p][r], 0.f);
                v += __shfl_xor(v, 1); v += __shfl_xor(v, 2);
                v += __shfl_xor(v, 4); v += __shfl_xor(v, 8);
                if (d == 0) {
                    int row = Mt * 32 + (r & 3) + 8 * (r >> 2) + 4 * sub;
                    int b   = gb + g * 4 + p * 2 + bp;
                    out[(size_t)b * 192 + 64 + row] = v;
                }
            }
        }
    }
}

extern "C" void kernel_launch(void* const* d_in, const int* in_sizes, int n_in,
                              void* d_out, int out_size, void* d_ws, size_t ws_size,
                              hipStream_t stream) {
    const float* x  = (const float*)d_in[0];
    const float* W0 = (const float*)d_in[1];
    const float* b0 = (const float*)d_in[2];
    const float* W1 = (const float*)d_in[3];
    const float* b1 = (const float*)d_in[4];
    float* out = (float*)d_out;
    __half* Wp = (__half*)d_ws;   // 1.04 MB packed fragment-order weights

    prep_w<<<(WP_HALFS + 255) / 256, 256, 0, stream>>>(W0, W1, Wp);
    cin_main<<<B_ / 8, 256, 0, stream>>>(x, b0, b1, Wp, out);
}

// Round 5
// 81.445 us; speedup vs baseline: 1.0867x; 1.0867x over previous
//
#include <hip/hip_runtime.h>
#include <hip/hip_fp16.h>

// ---- problem constants ----
#define B_     4096
#define F_     39
#define NKK    130          // 13 segments x 10 kk (K=32 each); kk<50 layer0, rest layer1
#define KKPAD  131          // +1 slack kk so tail prefetch needs no clamp
#define WPANEL ((size_t)KKPAD * 128)   // f32x4 units per Mt panel

typedef _Float16 f16x8  __attribute__((ext_vector_type(8)));
typedef float    f32x4  __attribute__((ext_vector_type(4)));
typedef float    f32x16 __attribute__((ext_vector_type(16)));

union FragAB { f16x8 h8; __half2 h2[4]; f32x4 f4; unsigned u[4]; __half h[8]; };

// ---------- W pre-pack: Wp[Mt][kk][ks][lane][j] fp16 (A-fragment order) ----------
// 32x32x16 A-frag: row o = Mt*32+(lane&31), k = 8*sub + j (sub = lane>>5)
// layer0 (kk<50):  seg=kk/10, kkin=kk%10 -> h = 4*kkin+2*ks+sub (scalar side),
//                  m = seg*8+j (vector side);  W0[o][h*39+m], pads h==39 / m==39 -> 0
// layer1 (kk>=50): seg=(kk-50)/10, kkin=(kk-50)%10 -> m = 4*kkin+2*ks+sub (scalar),
//                  h = seg*8+j (vector);        W1[o][h*39+m], pad m==39 -> 0
__global__ __launch_bounds__(256) void prep_w(
    const float* __restrict__ W0, const float* __restrict__ W1,
    __half* __restrict__ Wp)
{
    int idx = blockIdx.x * 256 + threadIdx.x;   // logical over 4*130*1024
    if (idx >= 4 * 130 * 1024) return;
    int j    = idx & 7;
    int lane = (idx >> 3) & 63;
    int ks   = (idx >> 9) & 1;
    int rest = idx >> 10;
    int kk   = rest % 130, Mt = rest / 130;
    int o    = Mt * 32 + (lane & 31);
    int sub  = lane >> 5;
    float v = 0.f;
    if (kk < 50) {
        int seg = kk / 10, kkin = kk - seg * 10;
        int h = 4 * kkin + 2 * ks + sub;
        int m = seg * 8 + j;
        if (h < 39 && m < 39) v = W0[o * 1521 + h * 39 + m];
    } else {
        int l = kk - 50;
        int seg = l / 10, kkin = l - seg * 10;
        int m = 4 * kkin + 2 * ks + sub;
        int h = seg * 8 + j;
        if (m < 39) v = W1[o * 2496 + h * 39 + m];
    }
    Wp[((size_t)(Mt * KKPAD + kk) * 2 + ks) * 512 + lane * 8 + j] = __float2half(v);
}

// ---------- main: 1024 blocks x 256 thr (4 waves); wave = 32 rows (Mt=w) x 4 batches ----------
__global__ __launch_bounds__(256, 4) void cin_main(
    const float* __restrict__ x, const float* __restrict__ b0,
    const float* __restrict__ b1, const __half* __restrict__ Wp,
    float* __restrict__ out)
{
    __shared__ __align__(16) __half xT[4][16][40];    // 5 KB  [bt][d][f], f=39 zero pad
    __shared__ __align__(16) __half nhT[4][16][68];   // 8.5 KB [bt][d][h]
    __shared__ float bs0[128], bs1[128];              // 1 KB bias

    const int t    = threadIdx.x;
    const int w    = t >> 6, lane = t & 63;           // w = Mt tile
    const int sub  = lane >> 5, bp = (lane >> 4) & 1, d = lane & 15;
    const int gb   = blockIdx.x * 4;

    if (t < 128) { bs0[t] = b0[t]; bs1[t] = b1[t]; }

    // xT fill: x[b][f][d] f32 -> xT[bt][d][f] fp16
    for (int i = t; i < 624; i += 256) {
        int bt = i / 156, r2 = i - bt * 156;
        int f = r2 >> 2, dq = r2 & 3;
        float4 v = *(const float4*)&x[((size_t)(gb + bt) * F_ + f) * 16 + dq * 4];
        xT[bt][dq * 4 + 0][f] = __float2half(v.x);
        xT[bt][dq * 4 + 1][f] = __float2half(v.y);
        xT[bt][dq * 4 + 2][f] = __float2half(v.z);
        xT[bt][dq * 4 + 3][f] = __float2half(v.w);
    }
    if (t < 64) xT[t >> 4][t & 15][39] = __float2half(0.f);
    __syncthreads();

    // register-resident x rows (per lane: its 2 batches 2p+bp), 40 VGPR
    FragAB xmc[2][5];
#pragma unroll
    for (int p = 0; p < 2; ++p)
#pragma unroll
        for (int a = 0; a < 5; ++a)
            xmc[p][a].f4 = *(const f32x4*)&xT[2 * p + bp][d][a * 8];

    // v_perm selector: broadcast lo half (sub=0) or hi half (sub=1) of a u32
    const unsigned psel = sub ? 0x03020302u : 0x01000100u;

    // acc init = b0 (C/D: col = lane&31 = bp*16+d -> batch/d; row = (r&3)+8*(r>>2)+4*sub)
    f32x16 acc[2];   // [pair]
#pragma unroll
    for (int r = 0; r < 16; ++r) {
        float bv = bs0[w * 32 + (r & 3) + 8 * (r >> 2) + 4 * sub];
        acc[0][r] = bv; acc[1][r] = bv;
    }

    // per-wave contiguous A-panel stream (registers, no LDS, no barriers)
    const f32x4* Ap = (const f32x4*)Wp + (size_t)w * WPANEL + lane;
    FragAB Ac0, Ac1;
    Ac0.f4 = Ap[0];
    Ac1.f4 = Ap[64];

    int kk = 0;
#pragma unroll 1
    for (int seg = 0; seg < 13; ++seg) {
        if (seg == 5) {
            // ---- layer0 -> layer1 transition ----
            if (w < 2) {
                // rows 0..63 -> nhT (fp16)
#pragma unroll
                for (int p = 0; p < 2; ++p) {
                    __half* nr = &nhT[2 * p + bp][d][0];
#pragma unroll
                    for (int rq = 0; rq < 4; ++rq) {
                        union { __half h[4]; float2 f2; } pk;
#pragma unroll
                        for (int q = 0; q < 4; ++q)
                            pk.h[q] = __float2half(fmaxf(acc[p][rq * 4 + q], 0.f));
                        *(float2*)(nr + w * 32 + 8 * rq + 4 * sub) = pk.f2;
                    }
                }
            } else {
                // rows 64..127 -> direct0 (out cols 0..63): reduce over d
#pragma unroll
                for (int p = 0; p < 2; ++p) {
#pragma unroll
                    for (int rq = 0; rq < 4; ++rq) {
                        float4 s; float* sv = (float*)&s;
#pragma unroll
                        for (int q = 0; q < 4; ++q) {
                            float v = fmaxf(acc[p][rq * 4 + q], 0.f);
                            v += __shfl_xor(v, 1); v += __shfl_xor(v, 2);
                            v += __shfl_xor(v, 4); v += __shfl_xor(v, 8);
                            sv[q] = v;
                        }
                        if (d == 0) {
                            int row = w * 32 + 8 * rq + 4 * sub;     // 64..127
                            *(float4*)&out[(size_t)(gb + 2 * p + bp) * 192 + (row - 64)] = s;
                        }
                    }
                }
            }
#pragma unroll
            for (int r = 0; r < 16; ++r) {
                float bv = bs1[w * 32 + (r & 3) + 8 * (r >> 2) + 4 * sub];
                acc[0][r] = bv; acc[1][r] = bv;
            }
            __syncthreads();   // nhT visible
        }

        // per-segment vector operand: layer0 = x m-slice, layer1 = nh h-slice
        FragAB xcur[2];
        if (seg < 5) {
#pragma unroll
            for (int p = 0; p < 2; ++p)
                xcur[p].f4 = *(const f32x4*)&xT[2 * p + bp][d][seg * 8];
        } else {
#pragma unroll
            for (int p = 0; p < 2; ++p)
                xcur[p].f4 = *(const f32x4*)&nhT[2 * p + bp][d][(seg - 5) * 8];
        }

#pragma unroll
        for (int kkin = 0; kkin < 10; ++kkin) {
            // prefetch next kk's A-frags (slack row at kk=130 -> no clamp)
            FragAB An0, An1;
            An0.f4 = Ap[(size_t)(kk + 1) * 128];
            An1.f4 = Ap[(size_t)(kk + 1) * 128 + 64];

            __builtin_amdgcn_s_setprio(1);
#pragma unroll
            for (int ks = 0; ks < 2; ++ks) {
                const int ee = 2 * kkin + ks;   // compile-time
#pragma unroll
                for (int p = 0; p < 2; ++p) {
                    unsigned bc = __builtin_amdgcn_perm(0u, xmc[p][ee >> 2].u[ee & 3], psel);
                    __half2 xh2 = *(__half2*)&bc;
                    FragAB bfr;
#pragma unroll
                    for (int q = 0; q < 4; ++q)
                        bfr.h2[q] = __hmul2(xcur[p].h2[q], xh2);
                    acc[p] = __builtin_amdgcn_mfma_f32_32x32x16_f16(
                        ks ? Ac1.h8 : Ac0.h8, bfr.h8, acc[p], 0, 0, 0);
                }
            }
            __builtin_amdgcn_s_setprio(0);
            Ac0 = An0; Ac1 = An1;
            ++kk;
        }
    }

    // ---- final epilogue: direct1 -> out cols 64..191 (all waves) ----
#pragma unroll
    for (int p = 0; p < 2; ++p) {
#pragma unroll
        for (int rq = 0; rq < 4; ++rq) {
            float4 s; float* sv = (float*)&s;
#pragma unroll
            for (int q = 0; q < 4; ++q) {
                float v = fmaxf(acc[p][rq * 4 + q], 0.f);
                v += __shfl_xor(v, 1); v += __shfl_xor(v, 2);
                v += __shfl_xor(v, 4); v += __shfl_xor(v, 8);
                sv[q] = v;
            }
            if (d == 0) {
                int row = w * 32 + 8 * rq + 4 * sub;
                *(float4*)&out[(size_t)(gb + 2 * p + bp) * 192 + 64 + row] = s;
            }
        }
    }
}

extern "C" void kernel_launch(void* const* d_in, const int* in_sizes, int n_in,
                              void* d_out, int out_size, void* d_ws, size_t ws_size,
                              hipStream_t stream) {
    const float* x  = (const float*)d_in[0];
    const float* W0 = (const float*)d_in[1];
    const float* b0 = (const float*)d_in[2];
    const float* W1 = (const float*)d_in[3];
    const float* b1 = (const float*)d_in[4];
    float* out = (float*)d_out;
    __half* Wp = (__half*)d_ws;   // 4 Mt-panels x 131 kk x 1024 halfs = 1.07 MB

    prep_w<<<(4 * 130 * 1024 + 255) / 256, 256, 0, stream>>>(W0, W1, Wp);
    cin_main<<<B_ / 4, 256, 0, stream>>>(x, b0, b1, Wp, out);
}

// Round 6
// 80.804 us; speedup vs baseline: 1.0953x; 1.0079x over previous
//
#include <hip/hip_runtime.h>
#include <hip/hip_fp16.h>

// ---- problem constants ----
#define B_     4096
#define F_     39
#define NKK    130          // 13 segments x 10 kk (K=32 each); kk<50 layer0, rest layer1
#define KKPAD  135          // +5 slack kk so depth-5 tail prefetch needs no clamp
#define PFD    5            // prefetch queue depth (10 % 5 == 0 -> compile-time slots)
#define WPANEL ((size_t)KKPAD * 128)   // f32x4 units per Mt panel

typedef _Float16 f16x8  __attribute__((ext_vector_type(8)));
typedef float    f32x4  __attribute__((ext_vector_type(4)));
typedef float    f32x16 __attribute__((ext_vector_type(16)));

union FragAB { f16x8 h8; __half2 h2[4]; f32x4 f4; unsigned u[4]; __half h[8]; };

// ---------- W pre-pack: Wp[Mt][kk][ks][lane][j] fp16 (A-fragment order) ----------
// 32x32x16 A-frag: row o = Mt*32+(lane&31), k = 8*sub + j (sub = lane>>5)
// layer0 (kk<50):  seg=kk/10, kkin=kk%10 -> h = 4*kkin+2*ks+sub (scalar side),
//                  m = seg*8+j (vector side);  W0[o][h*39+m], pads h==39 / m==39 -> 0
// layer1 (kk>=50): seg=(kk-50)/10, kkin=(kk-50)%10 -> m = 4*kkin+2*ks+sub (scalar),
//                  h = seg*8+j (vector);        W1[o][h*39+m], pad m==39 -> 0
__global__ __launch_bounds__(256) void prep_w(
    const float* __restrict__ W0, const float* __restrict__ W1,
    __half* __restrict__ Wp)
{
    int idx = blockIdx.x * 256 + threadIdx.x;   // logical over 4*130*1024
    if (idx >= 4 * 130 * 1024) return;
    int j    = idx & 7;
    int lane = (idx >> 3) & 63;
    int ks   = (idx >> 9) & 1;
    int rest = idx >> 10;
    int kk   = rest % 130, Mt = rest / 130;
    int o    = Mt * 32 + (lane & 31);
    int sub  = lane >> 5;
    float v = 0.f;
    if (kk < 50) {
        int seg = kk / 10, kkin = kk - seg * 10;
        int h = 4 * kkin + 2 * ks + sub;
        int m = seg * 8 + j;
        if (h < 39 && m < 39) v = W0[o * 1521 + h * 39 + m];
    } else {
        int l = kk - 50;
        int seg = l / 10, kkin = l - seg * 10;
        int m = 4 * kkin + 2 * ks + sub;
        int h = seg * 8 + j;
        if (m < 39) v = W1[o * 2496 + h * 39 + m];
    }
    Wp[((size_t)(Mt * KKPAD + kk) * 2 + ks) * 512 + lane * 8 + j] = __float2half(v);
}

// ---------- main: 1024 blocks x 256 thr (4 waves); wave = 32 rows (Mt=w) x 4 batches ----------
__global__ __launch_bounds__(256, 3) void cin_main(
    const float* __restrict__ x, const float* __restrict__ b0,
    const float* __restrict__ b1, const __half* __restrict__ Wp,
    float* __restrict__ out)
{
    __shared__ __align__(16) __half xT[4][16][40];    // 5 KB  [bt][d][f], f=39 zero pad
    __shared__ __align__(16) __half nhT[4][16][68];   // 8.5 KB [bt][d][h]
    __shared__ float bs0[128], bs1[128];              // 1 KB bias

    const int t    = threadIdx.x;
    const int w    = t >> 6, lane = t & 63;           // w = Mt tile
    const int sub  = lane >> 5, bp = (lane >> 4) & 1, d = lane & 15;
    const int gb   = blockIdx.x * 4;

    // per-wave contiguous A-panel stream; issue depth-5 prologue loads FIRST
    // (they complete under the xT staging + barrier)
    const f32x4* Ap = (const f32x4*)Wp + (size_t)w * WPANEL + lane;
    FragAB An[PFD][2];
#pragma unroll
    for (int i = 0; i < PFD; ++i) {
        An[i][0].f4 = Ap[(size_t)i * 128];
        An[i][1].f4 = Ap[(size_t)i * 128 + 64];
    }

    if (t < 128) { bs0[t] = b0[t]; bs1[t] = b1[t]; }

    // xT fill: x[b][f][d] f32 -> xT[bt][d][f] fp16
    for (int i = t; i < 624; i += 256) {
        int bt = i / 156, r2 = i - bt * 156;
        int f = r2 >> 2, dq = r2 & 3;
        float4 v = *(const float4*)&x[((size_t)(gb + bt) * F_ + f) * 16 + dq * 4];
        xT[bt][dq * 4 + 0][f] = __float2half(v.x);
        xT[bt][dq * 4 + 1][f] = __float2half(v.y);
        xT[bt][dq * 4 + 2][f] = __float2half(v.z);
        xT[bt][dq * 4 + 3][f] = __float2half(v.w);
    }
    if (t < 64) xT[t >> 4][t & 15][39] = __float2half(0.f);
    __syncthreads();

    // register-resident x rows (per lane: its 2 batches 2p+bp), 40 VGPR
    FragAB xmc[2][5];
#pragma unroll
    for (int p = 0; p < 2; ++p)
#pragma unroll
        for (int a = 0; a < 5; ++a)
            xmc[p][a].f4 = *(const f32x4*)&xT[2 * p + bp][d][a * 8];

    // v_perm selector: broadcast lo half (sub=0) or hi half (sub=1) of a u32
    const unsigned psel = sub ? 0x03020302u : 0x01000100u;

    // acc init = b0 (C/D: col = lane&31 = bp*16+d; row = (r&3)+8*(r>>2)+4*sub)
    f32x16 acc[2];   // [pair]
#pragma unroll
    for (int r = 0; r < 16; ++r) {
        float bv = bs0[w * 32 + (r & 3) + 8 * (r >> 2) + 4 * sub];
        acc[0][r] = bv; acc[1][r] = bv;
    }

    int kk = 0;
#pragma unroll 1
    for (int seg = 0; seg < 13; ++seg) {
        if (seg == 5) {
            // ---- layer0 -> layer1 transition ----
            if (w < 2) {
                // rows 0..63 -> nhT (fp16)
#pragma unroll
                for (int p = 0; p < 2; ++p) {
                    __half* nr = &nhT[2 * p + bp][d][0];
#pragma unroll
                    for (int rq = 0; rq < 4; ++rq) {
                        union { __half h[4]; float2 f2; } pk;
#pragma unroll
                        for (int q = 0; q < 4; ++q)
                            pk.h[q] = __float2half(fmaxf(acc[p][rq * 4 + q], 0.f));
                        *(float2*)(nr + w * 32 + 8 * rq + 4 * sub) = pk.f2;
                    }
                }
            } else {
                // rows 64..127 -> direct0 (out cols 0..63): reduce over d
#pragma unroll
                for (int p = 0; p < 2; ++p) {
#pragma unroll
                    for (int rq = 0; rq < 4; ++rq) {
                        float4 s; float* sv = (float*)&s;
#pragma unroll
                        for (int q = 0; q < 4; ++q) {
                            float v = fmaxf(acc[p][rq * 4 + q], 0.f);
                            v += __shfl_xor(v, 1); v += __shfl_xor(v, 2);
                            v += __shfl_xor(v, 4); v += __shfl_xor(v, 8);
                            sv[q] = v;
                        }
                        if (d == 0) {
                            int row = w * 32 + 8 * rq + 4 * sub;     // 64..127
                            *(float4*)&out[(size_t)(gb + 2 * p + bp) * 192 + (row - 64)] = s;
                        }
                    }
                }
            }
#pragma unroll
            for (int r = 0; r < 16; ++r) {
                float bv = bs1[w * 32 + (r & 3) + 8 * (r >> 2) + 4 * sub];
                acc[0][r] = bv; acc[1][r] = bv;
            }
            __syncthreads();   // nhT visible (drains vmcnt once; queue refills below)
        }

        // per-segment vector operand: layer0 = x m-slice, layer1 = nh h-slice
        FragAB xcur[2];
        if (seg < 5) {
#pragma unroll
            for (int p = 0; p < 2; ++p)
                xcur[p].f4 = *(const f32x4*)&xT[2 * p + bp][d][seg * 8];
        } else {
#pragma unroll
            for (int p = 0; p < 2; ++p)
                xcur[p].f4 = *(const f32x4*)&nhT[2 * p + bp][d][(seg - 5) * 8];
        }

#pragma unroll
        for (int kkin = 0; kkin < 10; ++kkin) {
            const int s = kkin % PFD;   // compile-time (kk%5 == kkin%5 since 10%5==0)

            __builtin_amdgcn_s_setprio(1);
#pragma unroll
            for (int ks = 0; ks < 2; ++ks) {
                const int ee = 2 * kkin + ks;   // compile-time
#pragma unroll
                for (int p = 0; p < 2; ++p) {
                    unsigned bc = __builtin_amdgcn_perm(0u, xmc[p][ee >> 2].u[ee & 3], psel);
                    __half2 xh2 = *(__half2*)&bc;
                    FragAB bfr;
#pragma unroll
                    for (int q = 0; q < 4; ++q)
                        bfr.h2[q] = __hmul2(xcur[p].h2[q], xh2);
                    acc[p] = __builtin_amdgcn_mfma_f32_32x32x16_f16(
                        An[s][ks].h8, bfr.h8, acc[p], 0, 0, 0);
                }
            }
            __builtin_amdgcn_s_setprio(0);

            // reload same slot for kk+PFD (pad rows 130..134 -> no clamp needed)
            An[s][0].f4 = Ap[(size_t)(kk + PFD) * 128];
            An[s][1].f4 = Ap[(size_t)(kk + PFD) * 128 + 64];
            ++kk;
        }
    }

    // ---- final epilogue: direct1 -> out cols 64..191 (all waves) ----
#pragma unroll
    for (int p = 0; p < 2; ++p) {
#pragma unroll
        for (int rq = 0; rq < 4; ++rq) {
            float4 s; float* sv = (float*)&s;
#pragma unroll
            for (int q = 0; q < 4; ++q) {
                float v = fmaxf(acc[p][rq * 4 + q], 0.f);
                v += __shfl_xor(v, 1); v += __shfl_xor(v, 2);
                v += __shfl_xor(v, 4); v += __shfl_xor(v, 8);
                sv[q] = v;
            }
            if (d == 0) {
                int row = w * 32 + 8 * rq + 4 * sub;
                *(float4*)&out[(size_t)(gb + 2 * p + bp) * 192 + 64 + row] = s;
            }
        }
    }
}

extern "C" void kernel_launch(void* const* d_in, const int* in_sizes, int n_in,
                              void* d_out, int out_size, void* d_ws, size_t ws_size,
                              hipStream_t stream) {
    const float* x  = (const float*)d_in[0];
    const float* W0 = (const float*)d_in[1];
    const float* b0 = (const float*)d_in[2];
    const float* W1 = (const float*)d_in[3];
    const float* b1 = (const float*)d_in[4];
    float* out = (float*)d_out;
    __half* Wp = (__half*)d_ws;   // 4 Mt-panels x 135 kk x 1024 halfs = 1.11 MB

    prep_w<<<(4 * 130 * 1024 + 255) / 256, 256, 0, stream>>>(W0, W1, Wp);
    cin_main<<<B_ / 4, 256, 0, stream>>>(x, b0, b1, Wp, out);
}

// Round 7
// 74.120 us; speedup vs baseline: 1.1941x; 1.0902x over previous
//
#include <hip/hip_runtime.h>
#include <hip/hip_fp16.h>

// ---- problem constants ----
#define B_     4096
#define F_     39
#define NKK    130          // 13 segments x 10 kk (K=32 each); kk<50 layer0, rest layer1
#define KKPAD  132          // +2 slack kk so depth-2 tail prefetch needs no clamp
#define PFD    2            // prefetch queue depth (10 % 2 == 0 -> compile-time slots)
#define WPANEL ((size_t)KKPAD * 128)   // f32x4 units per Mt panel

typedef _Float16 f16x8  __attribute__((ext_vector_type(8)));
typedef float    f32x4  __attribute__((ext_vector_type(4)));
typedef float    f32x16 __attribute__((ext_vector_type(16)));

union FragAB { f16x8 h8; __half2 h2[4]; f32x4 f4; unsigned u[4]; __half h[8]; };

// ---------- W pre-pack: Wp[Mt][kk][ks][lane][j] fp16 (A-fragment order) ----------
// 32x32x16 A-frag: row o = Mt*32+(lane&31), k = 8*sub + j (sub = lane>>5)
// layer0 (kk<50):  seg=kk/10, kkin=kk%10 -> h = 4*kkin+2*ks+sub (scalar side),
//                  m = seg*8+j (vector side);  W0[o][h*39+m], pads h==39 / m==39 -> 0
// layer1 (kk>=50): seg=(kk-50)/10, kkin=(kk-50)%10 -> m = 4*kkin+2*ks+sub (scalar),
//                  h = seg*8+j (vector);        W1[o][h*39+m], pad m==39 -> 0
__global__ __launch_bounds__(256) void prep_w(
    const float* __restrict__ W0, const float* __restrict__ W1,
    __half* __restrict__ Wp)
{
    int idx = blockIdx.x * 256 + threadIdx.x;   // logical over 4*130*1024
    if (idx >= 4 * 130 * 1024) return;
    int j    = idx & 7;
    int lane = (idx >> 3) & 63;
    int ks   = (idx >> 9) & 1;
    int rest = idx >> 10;
    int kk   = rest % 130, Mt = rest / 130;
    int o    = Mt * 32 + (lane & 31);
    int sub  = lane >> 5;
    float v = 0.f;
    if (kk < 50) {
        int seg = kk / 10, kkin = kk - seg * 10;
        int h = 4 * kkin + 2 * ks + sub;
        int m = seg * 8 + j;
        if (h < 39 && m < 39) v = W0[o * 1521 + h * 39 + m];
    } else {
        int l = kk - 50;
        int seg = l / 10, kkin = l - seg * 10;
        int m = 4 * kkin + 2 * ks + sub;
        int h = seg * 8 + j;
        if (m < 39) v = W1[o * 2496 + h * 39 + m];
    }
    Wp[((size_t)(Mt * KKPAD + kk) * 2 + ks) * 512 + lane * 8 + j] = __float2half(v);
}

// ---------- main: 512 blocks x 256 thr (4 waves); wave = 32 rows (Mt=w) x 8 batches ----------
__global__ __launch_bounds__(256, 2) void cin_main(
    const float* __restrict__ x, const float* __restrict__ b0,
    const float* __restrict__ b1, const __half* __restrict__ Wp,
    float* __restrict__ out)
{
    __shared__ __align__(16) __half xT[8][16][40];    // 10 KB  [bt][d][f], f=39 zero pad
    __shared__ __align__(16) __half nhT[8][16][68];   // 17 KB  [bt][d][h]
    __shared__ float bs0[128], bs1[128];              // 1 KB bias

    const int t    = threadIdx.x;
    const int w    = t >> 6, lane = t & 63;           // w = Mt tile
    const int sub  = lane >> 5, bp = (lane >> 4) & 1, d = lane & 15;
    const int gb   = blockIdx.x * 8;

    // per-wave contiguous A-panel stream; issue depth-2 prologue loads FIRST
    // (they complete under the xT staging + barrier)
    const f32x4* Ap = (const f32x4*)Wp + (size_t)w * WPANEL + lane;
    FragAB An[PFD][2];
#pragma unroll
    for (int i = 0; i < PFD; ++i) {
        An[i][0].f4 = Ap[(size_t)i * 128];
        An[i][1].f4 = Ap[(size_t)i * 128 + 64];
    }

    if (t < 128) { bs0[t] = b0[t]; bs1[t] = b1[t]; }

    // xT fill: x[b][f][d] f32 -> xT[bt][d][f] fp16  (8 batches)
    for (int i = t; i < 1248; i += 256) {
        int bt = i / 156, r2 = i - bt * 156;
        int f = r2 >> 2, dq = r2 & 3;
        float4 v = *(const float4*)&x[((size_t)(gb + bt) * F_ + f) * 16 + dq * 4];
        xT[bt][dq * 4 + 0][f] = __float2half(v.x);
        xT[bt][dq * 4 + 1][f] = __float2half(v.y);
        xT[bt][dq * 4 + 2][f] = __float2half(v.z);
        xT[bt][dq * 4 + 3][f] = __float2half(v.w);
    }
    if (t < 128) xT[t >> 4][t & 15][39] = __float2half(0.f);
    __syncthreads();

    // register-resident x rows (per lane: its 4 batches 2p+bp), 80 VGPR
    FragAB xmc[4][5];
#pragma unroll
    for (int p = 0; p < 4; ++p)
#pragma unroll
        for (int a = 0; a < 5; ++a)
            xmc[p][a].f4 = *(const f32x4*)&xT[2 * p + bp][d][a * 8];

    // v_perm selector: broadcast lo half (sub=0) or hi half (sub=1) of a u32
    const unsigned psel = sub ? 0x03020302u : 0x01000100u;

    // acc init = b0 (C/D: col = lane&31 = bp*16+d; row = (r&3)+8*(r>>2)+4*sub)
    f32x16 acc[4];   // [pair p] -> batch 2p+bp
#pragma unroll
    for (int r = 0; r < 16; ++r) {
        float bv = bs0[w * 32 + (r & 3) + 8 * (r >> 2) + 4 * sub];
#pragma unroll
        for (int p = 0; p < 4; ++p) acc[p][r] = bv;
    }

    int kk = 0;
#pragma unroll 1
    for (int seg = 0; seg < 13; ++seg) {
        if (seg == 5) {
            // ---- layer0 -> layer1 transition ----
            if (w < 2) {
                // rows 0..63 -> nhT (fp16)
#pragma unroll
                for (int p = 0; p < 4; ++p) {
                    __half* nr = &nhT[2 * p + bp][d][0];
#pragma unroll
                    for (int rq = 0; rq < 4; ++rq) {
                        union { __half h[4]; float2 f2; } pk;
#pragma unroll
                        for (int q = 0; q < 4; ++q)
                            pk.h[q] = __float2half(fmaxf(acc[p][rq * 4 + q], 0.f));
                        *(float2*)(nr + w * 32 + 8 * rq + 4 * sub) = pk.f2;
                    }
                }
            } else {
                // rows 64..127 -> direct0 (out cols 0..63): reduce over d
#pragma unroll
                for (int p = 0; p < 4; ++p) {
#pragma unroll
                    for (int rq = 0; rq < 4; ++rq) {
                        float4 s; float* sv = (float*)&s;
#pragma unroll
                        for (int q = 0; q < 4; ++q) {
                            float v = fmaxf(acc[p][rq * 4 + q], 0.f);
                            v += __shfl_xor(v, 1); v += __shfl_xor(v, 2);
                            v += __shfl_xor(v, 4); v += __shfl_xor(v, 8);
                            sv[q] = v;
                        }
                        if (d == 0) {
                            int row = w * 32 + 8 * rq + 4 * sub;     // 64..127
                            *(float4*)&out[(size_t)(gb + 2 * p + bp) * 192 + (row - 64)] = s;
                        }
                    }
                }
            }
#pragma unroll
            for (int r = 0; r < 16; ++r) {
                float bv = bs1[w * 32 + (r & 3) + 8 * (r >> 2) + 4 * sub];
#pragma unroll
                for (int p = 0; p < 4; ++p) acc[p][r] = bv;
            }
            __syncthreads();   // nhT visible (drains vmcnt once; queue refills below)
        }

        // per-segment vector operand: layer0 = x m-slice, layer1 = nh h-slice
        FragAB xcur[4];
        if (seg < 5) {
#pragma unroll
            for (int p = 0; p < 4; ++p)
                xcur[p].f4 = *(const f32x4*)&xT[2 * p + bp][d][seg * 8];
        } else {
#pragma unroll
            for (int p = 0; p < 4; ++p)
                xcur[p].f4 = *(const f32x4*)&nhT[2 * p + bp][d][(seg - 5) * 8];
        }

#pragma unroll
        for (int kkin = 0; kkin < 10; ++kkin) {
            const int s = kkin & 1;   // compile-time (kk%2 == kkin%2 since 10%2==0)

            __builtin_amdgcn_s_setprio(1);
#pragma unroll
            for (int ks = 0; ks < 2; ++ks) {
                const int ee = 2 * kkin + ks;   // compile-time
#pragma unroll
                for (int p = 0; p < 4; ++p) {
                    unsigned bc = __builtin_amdgcn_perm(0u, xmc[p][ee >> 2].u[ee & 3], psel);
                    __half2 xh2 = *(__half2*)&bc;
                    FragAB bfr;
#pragma unroll
                    for (int q = 0; q < 4; ++q)
                        bfr.h2[q] = __hmul2(xcur[p].h2[q], xh2);
                    acc[p] = __builtin_amdgcn_mfma_f32_32x32x16_f16(
                        An[s][ks].h8, bfr.h8, acc[p], 0, 0, 0);
                }
            }
            __builtin_amdgcn_s_setprio(0);

            // reload same slot for kk+PFD (pad rows 130..131 -> no clamp needed)
            An[s][0].f4 = Ap[(size_t)(kk + PFD) * 128];
            An[s][1].f4 = Ap[(size_t)(kk + PFD) * 128 + 64];
            ++kk;
        }
    }

    // ---- final epilogue: direct1 -> out cols 64..191 (all waves) ----
#pragma unroll
    for (int p = 0; p < 4; ++p) {
#pragma unroll
        for (int rq = 0; rq < 4; ++rq) {
            float4 s; float* sv = (float*)&s;
#pragma unroll
            for (int q = 0; q < 4; ++q) {
                float v = fmaxf(acc[p][rq * 4 + q], 0.f);
                v += __shfl_xor(v, 1); v += __shfl_xor(v, 2);
                v += __shfl_xor(v, 4); v += __shfl_xor(v, 8);
                sv[q] = v;
            }
            if (d == 0) {
                int row = w * 32 + 8 * rq + 4 * sub;
                *(float4*)&out[(size_t)(gb + 2 * p + bp) * 192 + 64 + row] = s;
            }
        }
    }
}

extern "C" void kernel_launch(void* const* d_in, const int* in_sizes, int n_in,
                              void* d_out, int out_size, void* d_ws, size_t ws_size,
                              hipStream_t stream) {
    const float* x  = (const float*)d_in[0];
    const float* W0 = (const float*)d_in[1];
    const float* b0 = (const float*)d_in[2];
    const float* W1 = (const float*)d_in[3];
    const float* b1 = (const float*)d_in[4];
    float* out = (float*)d_out;
    __half* Wp = (__half*)d_ws;   // 4 Mt-panels x 132 kk x 1024 halfs = 1.08 MB

    prep_w<<<(4 * 130 * 1024 + 255) / 256, 256, 0, stream>>>(W0, W1, Wp);
    cin_main<<<B_ / 8, 256, 0, stream>>>(x, b0, b1, Wp, out);
}